// Round 7
// baseline (175.905 us; speedup 1.0000x reference)
//
#include <hip/hip_runtime.h>

#define BB 8
#define SS 2048
#define DD 1024
#define BDD 512
#define NSP 64

typedef __attribute__((ext_vector_type(8))) short bf16x8;
typedef __attribute__((ext_vector_type(4))) float f32x4;
typedef unsigned short u16;
typedef unsigned int u32;

__device__ __forceinline__ u16 f2bf(float f) {
  u32 u = __builtin_bit_cast(u32, f);
  u = u + 0x7fffu + ((u >> 16) & 1u);
  return (u16)(u >> 16);
}

__device__ __forceinline__ void gl_lds16(const void* g, void* l) {
  __builtin_amdgcn_global_load_lds((const __attribute__((address_space(1))) void*)g,
                                   (__attribute__((address_space(3))) void*)l,
                                   16, 0, 0);
}

// ---------- fused: tok f32 -> tokbf (bf16 row-major) + tokT (bf16 [b][d][s]) ----------
__global__ void k_prep_tok(const float* __restrict__ tok, u16* __restrict__ tokbf,
                           u16* __restrict__ tokT) {
  __shared__ u16 tile[64][80];
  int C0 = blockIdx.x * 64;
  int R0 = blockIdx.y * 64;
  int b = R0 >> 11, s0 = R0 & 2047;
  int t = threadIdx.x;
  int lr = t >> 3, lc = (t & 7) * 8;
#pragma unroll
  for (int i = 0; i < 2; ++i) {
    int r = lr + i * 32;
    const float* src = tok + (size_t)(R0 + r) * DD + C0 + lc;
    float4 a = *(const float4*)src;
    float4 bq = *(const float4*)(src + 4);
    uint4 v;
    v.x = f2bf(a.x) | ((u32)f2bf(a.y) << 16);
    v.y = f2bf(a.z) | ((u32)f2bf(a.w) << 16);
    v.z = f2bf(bq.x) | ((u32)f2bf(bq.y) << 16);
    v.w = f2bf(bq.z) | ((u32)f2bf(bq.w) << 16);
    *(uint4*)(tokbf + (size_t)(R0 + r) * DD + C0 + lc) = v;
    *(uint4*)&tile[r][lc] = v;
  }
  __syncthreads();
  int sseg = (t & 7) * 8;
#pragma unroll
  for (int i = 0; i < 2; ++i) {
    int dcol = (t >> 3) + i * 32;
    u16 a0 = tile[sseg + 0][dcol], a1 = tile[sseg + 1][dcol];
    u16 a2 = tile[sseg + 2][dcol], a3 = tile[sseg + 3][dcol];
    u16 a4 = tile[sseg + 4][dcol], a5 = tile[sseg + 5][dcol];
    u16 a6 = tile[sseg + 6][dcol], a7 = tile[sseg + 7][dcol];
    uint4 v;
    v.x = a0 | ((u32)a1 << 16);
    v.y = a2 | ((u32)a3 << 16);
    v.z = a4 | ((u32)a5 << 16);
    v.w = a6 | ((u32)a7 << 16);
    *(uint4*)(tokT + (size_t)b * DD * SS + (size_t)(C0 + dcol) * SS + s0 + sseg) = v;
  }
}

// ---------- fused: infl f32 -> inflbf + inflT + per-tile column sums ----------
__global__ void k_prep_infl(const float* __restrict__ infl, u16* __restrict__ inflbf,
                            u16* __restrict__ inflT, float* __restrict__ rsum) {
  __shared__ u16 tile[64][80];
  __shared__ float ps[32][64];
  int R0 = blockIdx.x * 64;
  int b = R0 >> 11, s0 = R0 & 2047;
  int st = s0 >> 6;
  int t = threadIdx.x;
  int lr = t >> 3, lc = (t & 7) * 8;
  float col[8];
#pragma unroll
  for (int j = 0; j < 8; ++j) col[j] = 0.f;
#pragma unroll
  for (int i = 0; i < 2; ++i) {
    int r = lr + i * 32;
    const float* src = infl + (size_t)(R0 + r) * NSP + lc;
    float4 a = *(const float4*)src;
    float4 bq = *(const float4*)(src + 4);
    col[0] += a.x; col[1] += a.y; col[2] += a.z; col[3] += a.w;
    col[4] += bq.x; col[5] += bq.y; col[6] += bq.z; col[7] += bq.w;
    uint4 v;
    v.x = f2bf(a.x) | ((u32)f2bf(a.y) << 16);
    v.y = f2bf(a.z) | ((u32)f2bf(a.w) << 16);
    v.z = f2bf(bq.x) | ((u32)f2bf(bq.y) << 16);
    v.w = f2bf(bq.z) | ((u32)f2bf(bq.w) << 16);
    *(uint4*)(inflbf + (size_t)(R0 + r) * NSP + lc) = v;
    *(uint4*)&tile[r][lc] = v;
  }
#pragma unroll
  for (int j = 0; j < 8; ++j) ps[lr][lc + j] = col[j];
  __syncthreads();
  if (t < 64) {
    float s = 0.f;
#pragma unroll
    for (int rr = 0; rr < 32; ++rr) s += ps[rr][t];
    rsum[((size_t)b * 32 + st) * 64 + t] = s;
  }
  int sseg = (t & 7) * 8;
#pragma unroll
  for (int i = 0; i < 2; ++i) {
    int dcol = (t >> 3) + i * 32;
    u16 a0 = tile[sseg + 0][dcol], a1 = tile[sseg + 1][dcol];
    u16 a2 = tile[sseg + 2][dcol], a3 = tile[sseg + 3][dcol];
    u16 a4 = tile[sseg + 4][dcol], a5 = tile[sseg + 5][dcol];
    u16 a6 = tile[sseg + 6][dcol], a7 = tile[sseg + 7][dcol];
    uint4 v;
    v.x = a0 | ((u32)a1 << 16);
    v.y = a2 | ((u32)a3 << 16);
    v.z = a4 | ((u32)a5 << 16);
    v.w = a6 | ((u32)a7 << 16);
    *(uint4*)(inflT + ((size_t)b * NSP + dcol) * SS + s0 + sseg) = v;
  }
}

// ---------- finalize totals -> reciprocal ----------
__global__ void k_tot_fin(const float* __restrict__ rsum, float* __restrict__ rtot) {
  int t = threadIdx.x;  // 512 = 8b x 64k
  float s = 0.f;
#pragma unroll
  for (int st = 0; st < 32; ++st)
    s += rsum[((size_t)(t >> 6) * 32 + st) * 64 + (t & 63)];
  rtot[t] = 1.f / fmaxf(s, 1e-8f);
}

// ---------- gate_W [k][n] f32 -> gwt [n][k] bf16 ----------
__global__ void k_gatewt(const float* __restrict__ gw, u16* __restrict__ gwt) {
  __shared__ float tile[32][33];
  int n0 = blockIdx.x * 32, k0 = blockIdx.y * 32;
  int tx = threadIdx.x & 31, ty = threadIdx.x >> 5;
#pragma unroll
  for (int r = 0; r < 4; ++r) {
    int kr = ty + r * 8;
    tile[kr][tx] = gw[(k0 + kr) * DD + n0 + tx];
  }
  __syncthreads();
#pragma unroll
  for (int r = 0; r < 4; ++r) {
    int nc = ty + r * 8;
    gwt[(n0 + nc) * DD + k0 + tx] = f2bf(tile[tx][nc]);
  }
}

// ---------- MFMA gather partials: pg[sq][b*64+k][d] ----------
__global__ __launch_bounds__(256) void k_gather_mfma(const u16* __restrict__ inflT,
                                                     const u16* __restrict__ tokT,
                                                     float* __restrict__ pg) {
  __shared__ u16 As[64 * 64];
  __shared__ u16 Bs[64 * 64];
  int t = threadIdx.x;
  int l = t & 63, w = t >> 6;
  int wr = w >> 1, wc = w & 1;
  int n0 = blockIdx.x * 64;
  int b = blockIdx.y;
  int sq = blockIdx.z;
  int l15 = l & 15, lh = l >> 4;
  int srow = t >> 3, scol = (t & 7) * 8;

  const u16* ap = inflT + (size_t)b * NSP * SS;
  const u16* bp = tokT + (size_t)b * DD * SS;

  f32x4 acc[2][2];
#pragma unroll
  for (int i = 0; i < 2; ++i)
#pragma unroll
    for (int j = 0; j < 2; ++j) acc[i][j] = (f32x4){0.f, 0.f, 0.f, 0.f};

  for (int kt = 0; kt < 8; ++kt) {
    int k0 = sq * 512 + kt * 64;
#pragma unroll
    for (int i = 0; i < 2; ++i) {
      int row = srow + i * 32;
      gl_lds16(ap + row * SS + k0 + scol, &As[row * 64 + scol]);
      gl_lds16(bp + (n0 + row) * SS + k0 + scol, &Bs[row * 64 + scol]);
    }
    __syncthreads();
#pragma unroll
    for (int ks = 0; ks < 2; ++ks) {
      bf16x8 af[2], bfv[2];
#pragma unroll
      for (int mi = 0; mi < 2; ++mi)
        af[mi] = *(const bf16x8*)&As[(wr * 32 + mi * 16 + l15) * 64 + ks * 32 + lh * 8];
#pragma unroll
      for (int ni = 0; ni < 2; ++ni)
        bfv[ni] = *(const bf16x8*)&Bs[(wc * 32 + ni * 16 + l15) * 64 + ks * 32 + lh * 8];
#pragma unroll
      for (int mi = 0; mi < 2; ++mi)
#pragma unroll
        for (int ni = 0; ni < 2; ++ni)
          acc[mi][ni] = __builtin_amdgcn_mfma_f32_16x16x32_bf16(af[mi], bfv[ni], acc[mi][ni], 0, 0, 0);
    }
    __syncthreads();
  }

#pragma unroll
  for (int mi = 0; mi < 2; ++mi)
#pragma unroll
    for (int ni = 0; ni < 2; ++ni)
#pragma unroll
      for (int r = 0; r < 4; ++r) {
        int krow = wr * 32 + mi * 16 + lh * 4 + r;
        int dcol = n0 + wc * 32 + ni * 16 + l15;
        pg[((size_t)sq * 512 + b * NSP + krow) * DD + dcol] = acc[mi][ni][r];
      }
}

// ---------- enc partials (fused gather-reduce + rtot): pe[dq][m][n] ----------
__global__ void k_enc_part(const float* __restrict__ pg, const float* __restrict__ rtot,
                           const float* __restrict__ encW, float* __restrict__ pe) {
  __shared__ float gl[8][64];
  int dq = blockIdx.x, mt = blockIdx.y;
  int m0 = mt * 8, d0 = dq * 64;
  int t = threadIdx.x;
  {
    int r = t >> 5, c = t & 31;
    float s1 = 0.f, s2 = 0.f;
#pragma unroll
    for (int q = 0; q < 4; ++q) {
      const float* qp = pg + ((size_t)q * 512 + m0 + r) * DD + d0;
      s1 += qp[c]; s2 += qp[c + 32];
    }
    float rt = rtot[m0 + r];
    gl[r][c] = s1 * rt;
    gl[r][c + 32] = s2 * rt;
  }
  __syncthreads();
  int n4 = (t & 127) * 4, mh = (t >> 7) * 4;
  float4 acc[4];
#pragma unroll
  for (int m = 0; m < 4; ++m) acc[m] = (float4){0.f, 0.f, 0.f, 0.f};
  for (int i = 0; i < 64; ++i) {
    float4 wv = *(const float4*)(encW + (d0 + i) * BDD + n4);
#pragma unroll
    for (int m = 0; m < 4; ++m) {
      float g = gl[mh + m][i];
      acc[m].x += g * wv.x; acc[m].y += g * wv.y;
      acc[m].z += g * wv.z; acc[m].w += g * wv.w;
    }
  }
#pragma unroll
  for (int m = 0; m < 4; ++m)
    *(float4*)(pe + ((size_t)dq * 512 + m0 + mh + m) * BDD + n4) = acc[m];
}

// ---------- trans partials (fused enc-reduce + bias + relu): pt[dq][b*64+ks][e] ----------
__global__ void k_trans_part(const float* __restrict__ pe, const float* __restrict__ encB,
                             const float* __restrict__ trW, float* __restrict__ pt) {
  __shared__ float el[8][32];
  int dq = blockIdx.x, ks = blockIdx.y;
  int d0 = dq * 32;
  int t = threadIdx.x;
  {
    int r = t >> 5, c = t & 31;
    int m = r * NSP + ks;
    float s = 0.f;
#pragma unroll
    for (int p = 0; p < 16; ++p)
      s += pe[((size_t)p * 512 + m) * BDD + d0 + c];
    el[r][c] = fmaxf(s + encB[d0 + c], 0.f);
  }
  __syncthreads();
  int n4 = (t & 127) * 4, mh = (t >> 7) * 4;
  float4 acc[4];
#pragma unroll
  for (int m = 0; m < 4; ++m) acc[m] = (float4){0.f, 0.f, 0.f, 0.f};
  for (int i = 0; i < 32; ++i) {
    float4 wv = *(const float4*)(trW + ((size_t)ks * BDD + d0 + i) * BDD + n4);
#pragma unroll
    for (int m = 0; m < 4; ++m) {
      float g = el[mh + m][i];
      acc[m].x += g * wv.x; acc[m].y += g * wv.y;
      acc[m].z += g * wv.z; acc[m].w += g * wv.w;
    }
  }
#pragma unroll
  for (int m = 0; m < 4; ++m)
    *(float4*)(pt + ((size_t)dq * 512 + (mh + m) * NSP + ks) * BDD + n4) = acc[m];
}

// ---------- dec partials (fused trans-reduce + bias): pd[dq][m][n] ----------
__global__ void k_dec_part(const float* __restrict__ pt, const float* __restrict__ trB,
                           const float* __restrict__ decW, float* __restrict__ pd) {
  __shared__ float tl[8][64];
  int dq = blockIdx.x, mt = blockIdx.y;
  int m0 = mt * 8, d0 = dq * 64;
  int t = threadIdx.x;
  {
    int r = t >> 5, c = t & 31;
    int m = m0 + r;
    float s1 = 0.f, s2 = 0.f;
#pragma unroll
    for (int p = 0; p < 16; ++p) {
      const float* qp = pt + ((size_t)p * 512 + m) * BDD + d0;
      s1 += qp[c]; s2 += qp[c + 32];
    }
    tl[r][c] = s1 + trB[(m & 63) * BDD + d0 + c];
    tl[r][c + 32] = s2 + trB[(m & 63) * BDD + d0 + c + 32];
  }
  __syncthreads();
  int n4 = t * 4;
  float4 acc[8];
#pragma unroll
  for (int m = 0; m < 8; ++m) acc[m] = (float4){0.f, 0.f, 0.f, 0.f};
  for (int i = 0; i < 64; ++i) {
    float4 wv = *(const float4*)(decW + (d0 + i) * DD + n4);
#pragma unroll
    for (int m = 0; m < 8; ++m) {
      float g = tl[m][i];
      acc[m].x += g * wv.x; acc[m].y += g * wv.y;
      acc[m].z += g * wv.z; acc[m].w += g * wv.w;
    }
  }
#pragma unroll
  for (int m = 0; m < 8; ++m)
    *(float4*)(pd + ((size_t)dq * 512 + m0 + m) * DD + n4) = acc[m];
}

// ---------- reduce dec partials + bias -> decT[b][n][ks] bf16 ----------
__global__ void red_dec(const float* __restrict__ pd, const float* __restrict__ decB,
                        u16* __restrict__ decT) {
  __shared__ u16 st[64][34];
  int nt = blockIdx.x, b = blockIdx.y;
  int n0 = nt * 32;
  int t = threadIdx.x;
  int nn = t & 31, kg = t >> 5;
  float db = decB[n0 + nn];
#pragma unroll
  for (int ki = 0; ki < 8; ++ki) {
    int ks = kg * 8 + ki;
    float s = db;
#pragma unroll
    for (int p = 0; p < 8; ++p)
      s += pd[((size_t)p * 512 + b * NSP + ks) * DD + n0 + nn];
    st[ks][nn] = f2bf(s);
  }
  __syncthreads();
  int nr = t >> 3, kseg = (t & 7) * 8;
  uint4 v;
  v.x = st[kseg + 0][nr] | ((u32)st[kseg + 1][nr] << 16);
  v.y = st[kseg + 2][nr] | ((u32)st[kseg + 3][nr] << 16);
  v.z = st[kseg + 4][nr] | ((u32)st[kseg + 5][nr] << 16);
  v.w = st[kseg + 6][nr] | ((u32)st[kseg + 7][nr] << 16);
  *(uint4*)(decT + ((size_t)b * DD + n0 + nr) * NSP + kseg) = v;
}

// ---------- fused gate GEMM + scatter + sigmoid*flow ----------
// BM=128, BN=256, BK=64; 512 threads (8 waves 2x4); 3-slot LDS (144KB).
// Counted-vmcnt pipeline: tile T computes slot T%3 while issuing tile T+2's
// loads; per-tile wait = vmcnt(6) (never 0 in main loop). Per-phase barrier
// pairs (stage -> barrier -> setprio+MFMA -> barrier) for wave role-split.

#define STAGE_A(sl, k0, p)                                                  \
  { int e = (p)*512 + t; int row = e >> 3, csrc = ((e & 7) ^ (row & 7)) * 8; \
    gl_lds16(tokbf + (size_t)(m0 + row) * DD + (k0) + csrc, &As[sl][e * 8]); }
#define STAGE_B(sl, k0, p)                                                  \
  { int e = (p)*512 + t; int row = e >> 3, csrc = ((e & 7) ^ (row & 7)) * 8; \
    gl_lds16(gwt + (size_t)(n0 + row) * DD + (k0) + csrc, &Bs[sl][e * 8]); }

#define PHASE2(sl, ks, ACC, STAGE_STMT)                                      \
  {                                                                          \
    bf16x8 af[4], bfv[4];                                                    \
    int g = (ks)*4 + lh;                                                     \
    _Pragma("unroll")                                                        \
    for (int mi = 0; mi < 4; ++mi) {                                         \
      int r = wr * 64 + mi * 16 + l15;                                       \
      af[mi] = *(const bf16x8*)&As[sl][r * 64 + (g ^ (r & 7)) * 8];          \
    }                                                                        \
    _Pragma("unroll")                                                        \
    for (int ni = 0; ni < 4; ++ni) {                                         \
      int r = wc * 64 + ni * 16 + l15;                                       \
      bfv[ni] = *(const bf16x8*)&Bs[sl][r * 64 + (g ^ (r & 7)) * 8];         \
    }                                                                        \
    STAGE_STMT;                                                              \
    __builtin_amdgcn_s_barrier();                                            \
    __builtin_amdgcn_s_setprio(1);                                           \
    _Pragma("unroll")                                                        \
    for (int mi = 0; mi < 4; ++mi)                                           \
      _Pragma("unroll")                                                      \
      for (int ni = 0; ni < 4; ++ni)                                         \
        ACC[mi][ni] = __builtin_amdgcn_mfma_f32_16x16x32_bf16(af[mi], bfv[ni], ACC[mi][ni], 0, 0, 0); \
    __builtin_amdgcn_s_setprio(0);                                           \
  }

// full tile: compute slot sl, stage tile at k=sk into slot ssl, wait vmcnt(VM)
#define TILE_FULL(sl, ssl, sk, VMSTR)                                        \
  PHASE2(sl, 0, accg, { STAGE_A(ssl, sk, 0); STAGE_A(ssl, sk, 1);            \
                        STAGE_B(ssl, sk, 0); STAGE_B(ssl, sk, 1); });        \
  __builtin_amdgcn_s_barrier();                                              \
  PHASE2(sl, 1, accg, { STAGE_B(ssl, sk, 2); STAGE_B(ssl, sk, 3); });        \
  asm volatile("s_waitcnt " VMSTR ::: "memory");                             \
  __builtin_amdgcn_s_barrier();

#define TILE_NOST(sl, VMSTR)                                                 \
  PHASE2(sl, 0, accg, {});                                                   \
  __builtin_amdgcn_s_barrier();                                              \
  PHASE2(sl, 1, accg, {});                                                   \
  asm volatile("s_waitcnt " VMSTR ::: "memory");                             \
  __builtin_amdgcn_s_barrier();

__global__ __launch_bounds__(512, 2) void k_out(const u16* __restrict__ tokbf,
                                                const u16* __restrict__ gwt,
                                                const u16* __restrict__ inflbf,
                                                const u16* __restrict__ decT,
                                                const float* __restrict__ gateB,
                                                float* __restrict__ outp) {
  __shared__ u16 As[3][128 * 64];
  __shared__ u16 Bs[3][256 * 64];
  int t = threadIdx.x;
  int l = t & 63, w = t >> 6;
  int wr = w >> 2, wc = w & 3;  // 2 x 4 waves, 64x64 per wave
  int m0 = blockIdx.x * 128, n0 = blockIdx.y * 256;
  int l15 = l & 15, lh = l >> 4;

  f32x4 accg[4][4];
#pragma unroll
  for (int i = 0; i < 4; ++i)
#pragma unroll
    for (int j = 0; j < 4; ++j) accg[i][j] = (f32x4){0.f, 0.f, 0.f, 0.f};

  // prologue: tiles 0,1 in flight (6 loads each)
  STAGE_A(0, 0, 0); STAGE_A(0, 0, 1);
  STAGE_B(0, 0, 0); STAGE_B(0, 0, 1); STAGE_B(0, 0, 2); STAGE_B(0, 0, 3);
  STAGE_A(1, 64, 0); STAGE_A(1, 64, 1);
  STAGE_B(1, 64, 0); STAGE_B(1, 64, 1); STAGE_B(1, 64, 2); STAGE_B(1, 64, 3);
  asm volatile("s_waitcnt vmcnt(6)" ::: "memory");  // tile 0 landed; tile 1 in flight
  __builtin_amdgcn_s_barrier();

  // main: tiles 0..11, staging 2 ahead, vmcnt(6) per tile
#pragma unroll 1
  for (int i = 0; i < 4; ++i) {
    int kc = i * 192;
    TILE_FULL(0, 2, kc + 128, "vmcnt(6)");  // tile 3i   -> stages 3i+2
    TILE_FULL(1, 0, kc + 192, "vmcnt(6)");  // tile 3i+1 -> stages 3i+3
    TILE_FULL(2, 1, kc + 256, "vmcnt(6)");  // tile 3i+2 -> stages 3i+4
  }
  // tail: tiles 12..15
  TILE_FULL(0, 2, 896, "vmcnt(6)");  // tile 12 -> stages 14
  TILE_FULL(1, 0, 960, "vmcnt(6)");  // tile 13 -> stages 15
  TILE_NOST(2, "vmcnt(0)");          // tile 14; drain tile 15
  TILE_NOST(0, "vmcnt(0)");          // tile 15

  // scatter pass: K = 64 splats, stage into slot 0
  int b = m0 >> 11;
  int s0m = m0 & 2047;
#pragma unroll
  for (int p = 0; p < 2; ++p) {
    int e = p * 512 + t;
    int row = e >> 3, csrc = ((e & 7) ^ (row & 7)) * 8;
    gl_lds16(inflbf + ((size_t)b * SS + s0m + row) * NSP + csrc, &As[0][e * 8]);
  }
#pragma unroll
  for (int p = 0; p < 4; ++p) {
    int e = p * 512 + t;
    int row = e >> 3, csrc = ((e & 7) ^ (row & 7)) * 8;
    gl_lds16(decT + ((size_t)b * DD + n0 + row) * NSP + csrc, &Bs[0][e * 8]);
  }
  asm volatile("s_waitcnt vmcnt(0)" ::: "memory");
  __builtin_amdgcn_s_barrier();

  f32x4 accf[4][4];
#pragma unroll
  for (int i = 0; i < 4; ++i)
#pragma unroll
    for (int j = 0; j < 4; ++j) accf[i][j] = (f32x4){0.f, 0.f, 0.f, 0.f};
  PHASE2(0, 0, accf, {});
  __builtin_amdgcn_s_barrier();
  PHASE2(0, 1, accf, {});

  float gb[4];
#pragma unroll
  for (int ni = 0; ni < 4; ++ni) gb[ni] = gateB[n0 + wc * 64 + ni * 16 + l15];
#pragma unroll
  for (int mi = 0; mi < 4; ++mi)
#pragma unroll
    for (int ni = 0; ni < 4; ++ni)
#pragma unroll
      for (int r = 0; r < 4; ++r) {
        int mr = m0 + wr * 64 + mi * 16 + lh * 4 + r;
        int nc = n0 + wc * 64 + ni * 16 + l15;
        float z = accg[mi][ni][r] + gb[ni];
        float gate = 1.f / (1.f + __expf(-z));
        outp[(size_t)mr * DD + nc] = accf[mi][ni][r] * gate;
      }
}

extern "C" void kernel_launch(void* const* d_in, const int* in_sizes, int n_in,
                              void* d_out, int out_size, void* d_ws, size_t ws_size,
                              hipStream_t stream) {
  const float* tok = (const float*)d_in[0];
  const float* infl = (const float*)d_in[1];
  const float* encW = (const float*)d_in[2];
  const float* encB = (const float*)d_in[3];
  const float* trW = (const float*)d_in[4];
  const float* trB = (const float*)d_in[5];
  const float* decW = (const float*)d_in[6];
  const float* decB = (const float*)d_in[7];
  const float* gw = (const float*)d_in[8];
  const float* gateB = (const float*)d_in[9];
  float* outp = (float*)d_out;

  char* wsp = (char*)d_ws;
  u16* tokbf = (u16*)(wsp);                    // 33,554,432 B
  u16* gwt = (u16*)(wsp + 33554432);           //  2,097,152 B
  u16* inflbf = (u16*)(wsp + 35651584);        //  2,097,152 B
  float* rtot = (float*)(wsp + 37748736);      //      2,048 B
  u16* decT = (u16*)(wsp + 41945088);          //  1,048,576 B
  u16* tokT = (u16*)(wsp + 42993664);          // 33,554,432 B (dead after gather)
  float* pe = (float*)(wsp + 42993664);        //   overlays tokT[0:16MB]
  float* pt = (float*)(wsp + 42993664 + 16777216);  // overlays tokT[16:32MB]
  u16* inflT = (u16*)(wsp + 76548096);         //  2,097,152 B
  float* rsum = (float*)(wsp + 78645248);      //     65,536 B
  float* scratch = (float*)(wsp + 78710784);   // 16,777,216 B: pg then pd (end ~95.5 MB)

  k_prep_tok<<<dim3(16, 256), dim3(256), 0, stream>>>(tok, tokbf, tokT);
  k_prep_infl<<<dim3(256), dim3(256), 0, stream>>>(infl, inflbf, inflT, rsum);
  k_tot_fin<<<dim3(1), dim3(512), 0, stream>>>(rsum, rtot);
  k_gatewt<<<dim3(32, 32), dim3(256), 0, stream>>>(gw, gwt);
  k_gather_mfma<<<dim3(16, 8, 4), dim3(256), 0, stream>>>(inflT, tokT, scratch);
  k_enc_part<<<dim3(16, 64), dim3(256), 0, stream>>>(scratch, rtot, encW, pe);
  k_trans_part<<<dim3(16, 64), dim3(256), 0, stream>>>(pe, encB, trW, pt);
  k_dec_part<<<dim3(8, 64), dim3(256), 0, stream>>>(pt, trB, decW, scratch);
  red_dec<<<dim3(32, 8), dim3(256), 0, stream>>>(scratch, decB, decT);
  k_out<<<dim3(128, 4), dim3(512), 0, stream>>>(tokbf, gwt, inflbf, decT, gateB, outp);
}